// Round 2
// baseline (521.193 us; speedup 1.0000x reference)
//
#include <hip/hip_runtime.h>
#include <math.h>

typedef float f32x4 __attribute__((ext_vector_type(4)));
typedef int   i32x4 __attribute__((ext_vector_type(4)));

#define MAX_LDS_CAMS 1024   // 1024 cams * 48 B = 48 KB LDS

// ---------------------------------------------------------------------------
// Kernel 1: per-camera precompute. size cameras -> cams[c*12] = {R[9], t[3]}
// ---------------------------------------------------------------------------
__global__ void cam_precompute(const float* __restrict__ params,
                               float* __restrict__ cams, int size) {
    int c = blockIdx.x * blockDim.x + threadIdx.x;
    if (c >= size) return;
    float a  = params[6 * c + 0];
    float b  = params[6 * c + 1];
    float cc = params[6 * c + 2];
    float t2 = a * a + b * b + cc * cc;
    float t  = sqrtf(t2);
    float sin_c, cos_c;
    if (t < 1e-8f) {
        sin_c = 1.0f;
        cos_c = 0.5f;
    } else {
        sin_c = sinf(t) / t;
        cos_c = (1.0f - cosf(t)) / t2;
    }
    float sa = sin_c * a, sb = sin_c * b, sc = sin_c * cc;
    float cab = cos_c * a * b, cac = cos_c * a * cc, cbc = cos_c * b * cc;

    float* o = cams + 12 * c;
    // R = I + sin_c*K + cos_c*K*K,  K = [[0,a,b],[-a,0,c],[-b,-c,0]]
    o[0] = 1.0f - cos_c * (a * a + b * b);
    o[1] =  sa - cbc;
    o[2] =  sb + cac;
    o[3] = -sa - cbc;
    o[4] = 1.0f - cos_c * (a * a + cc * cc);
    o[5] =  sc - cab;
    o[6] = -sb + cac;
    o[7] = -sc - cab;
    o[8] = 1.0f - cos_c * (b * b + cc * cc);
    o[9]  = params[6 * c + 3];
    o[10] = params[6 * c + 4];
    o[11] = params[6 * c + 5];
}

// ---------------------------------------------------------------------------
// Kernel 2: streaming transform. 4 points per thread, all float4 I/O.
// Camera table staged in LDS; streaming I/O nontemporal.
// out layout (floats): [new_o: 3N][new_d: 3N][trans: 3N][R: 9N]
// ---------------------------------------------------------------------------
__launch_bounds__(256)
__global__ void cam_apply(const int* __restrict__ idx,
                          const f32x4* __restrict__ o4,
                          const f32x4* __restrict__ d4,
                          const f32x4* __restrict__ cams4,
                          float* __restrict__ out,
                          long long nq, long long N, int size) {
    __shared__ f32x4 scams[3 * MAX_LDS_CAMS];
    int tid = threadIdx.x;
    int nstage = (size < MAX_LDS_CAMS ? size : MAX_LDS_CAMS) * 3;
    for (int j = tid; j < nstage; j += 256)
        scams[j] = cams4[j];
    __syncthreads();

    long long t = blockIdx.x * 256LL + tid;
    if (t >= nq) return;
    long long base = 4LL * t;

    float ox[4], oy[4], oz[4], dx[4], dy[4], dz[4];
    int id[4];
    bool full = (base + 3 < N);

    if (full) {
        f32x4 A = __builtin_nontemporal_load(&o4[3 * t + 0]);
        f32x4 B = __builtin_nontemporal_load(&o4[3 * t + 1]);
        f32x4 C = __builtin_nontemporal_load(&o4[3 * t + 2]);
        ox[0] = A[0]; oy[0] = A[1]; oz[0] = A[2];
        ox[1] = A[3]; oy[1] = B[0]; oz[1] = B[1];
        ox[2] = B[2]; oy[2] = B[3]; oz[2] = C[0];
        ox[3] = C[1]; oy[3] = C[2]; oz[3] = C[3];
        A = __builtin_nontemporal_load(&d4[3 * t + 0]);
        B = __builtin_nontemporal_load(&d4[3 * t + 1]);
        C = __builtin_nontemporal_load(&d4[3 * t + 2]);
        dx[0] = A[0]; dy[0] = A[1]; dz[0] = A[2];
        dx[1] = A[3]; dy[1] = B[0]; dz[1] = B[1];
        dx[2] = B[2]; dy[2] = B[3]; dz[2] = C[0];
        dx[3] = C[1]; dy[3] = C[2]; dz[3] = C[3];
        i32x4 I4 = __builtin_nontemporal_load(&((const i32x4*)idx)[t]);
        id[0] = I4[0]; id[1] = I4[1]; id[2] = I4[2]; id[3] = I4[3];
    } else {
        const float* of = (const float*)o4;
        const float* df = (const float*)d4;
        for (int k = 0; k < 4; ++k) {
            long long n = base + k;
            if (n < N) {
                ox[k] = of[3 * n + 0]; oy[k] = of[3 * n + 1]; oz[k] = of[3 * n + 2];
                dx[k] = df[3 * n + 0]; dy[k] = df[3 * n + 1]; dz[k] = df[3 * n + 2];
                id[k] = idx[n];
            } else {
                ox[k] = oy[k] = oz[k] = dx[k] = dy[k] = dz[k] = 0.0f;
                id[k] = 0;
            }
        }
    }

    float no[12], nd[12], tr[12], Rm[36];
#pragma unroll
    for (int k = 0; k < 4; ++k) {
        int cid = id[k];
        f32x4 c0, c1, c2;
        if (cid < MAX_LDS_CAMS) {
            c0 = scams[3 * cid + 0];
            c1 = scams[3 * cid + 1];
            c2 = scams[3 * cid + 2];
        } else {
            c0 = cams4[3 * cid + 0];
            c1 = cams4[3 * cid + 1];
            c2 = cams4[3 * cid + 2];
        }
        float r00 = c0[0], r01 = c0[1], r02 = c0[2];
        float r10 = c0[3], r11 = c1[0], r12 = c1[1];
        float r20 = c1[2], r21 = c1[3], r22 = c2[0];
        float tx = c2[1], ty = c2[2], tz = c2[3];

        no[3 * k + 0] = r00 * ox[k] + r01 * oy[k] + r02 * oz[k] + tx;
        no[3 * k + 1] = r10 * ox[k] + r11 * oy[k] + r12 * oz[k] + ty;
        no[3 * k + 2] = r20 * ox[k] + r21 * oy[k] + r22 * oz[k] + tz;

        nd[3 * k + 0] = r00 * dx[k] + r01 * dy[k] + r02 * dz[k];
        nd[3 * k + 1] = r10 * dx[k] + r11 * dy[k] + r12 * dz[k];
        nd[3 * k + 2] = r20 * dx[k] + r21 * dy[k] + r22 * dz[k];

        tr[3 * k + 0] = tx; tr[3 * k + 1] = ty; tr[3 * k + 2] = tz;

        Rm[9 * k + 0] = r00; Rm[9 * k + 1] = r01; Rm[9 * k + 2] = r02;
        Rm[9 * k + 3] = r10; Rm[9 * k + 4] = r11; Rm[9 * k + 5] = r12;
        Rm[9 * k + 6] = r20; Rm[9 * k + 7] = r21; Rm[9 * k + 8] = r22;
    }

    if (full) {
        f32x4* p = (f32x4*)out + 3 * t;
        __builtin_nontemporal_store((f32x4){no[0], no[1], no[2],  no[3]},  &p[0]);
        __builtin_nontemporal_store((f32x4){no[4], no[5], no[6],  no[7]},  &p[1]);
        __builtin_nontemporal_store((f32x4){no[8], no[9], no[10], no[11]}, &p[2]);

        p = (f32x4*)(out + 3 * N) + 3 * t;
        __builtin_nontemporal_store((f32x4){nd[0], nd[1], nd[2],  nd[3]},  &p[0]);
        __builtin_nontemporal_store((f32x4){nd[4], nd[5], nd[6],  nd[7]},  &p[1]);
        __builtin_nontemporal_store((f32x4){nd[8], nd[9], nd[10], nd[11]}, &p[2]);

        p = (f32x4*)(out + 6 * N) + 3 * t;
        __builtin_nontemporal_store((f32x4){tr[0], tr[1], tr[2],  tr[3]},  &p[0]);
        __builtin_nontemporal_store((f32x4){tr[4], tr[5], tr[6],  tr[7]},  &p[1]);
        __builtin_nontemporal_store((f32x4){tr[8], tr[9], tr[10], tr[11]}, &p[2]);

        p = (f32x4*)(out + 9 * N) + 9 * t;
#pragma unroll
        for (int j = 0; j < 9; ++j)
            __builtin_nontemporal_store((f32x4){Rm[4 * j + 0], Rm[4 * j + 1],
                                                Rm[4 * j + 2], Rm[4 * j + 3]}, &p[j]);
    } else {
        for (int k = 0; k < 4; ++k) {
            long long n = base + k;
            if (n >= N) break;
            for (int j = 0; j < 3; ++j) {
                out[3 * n + j]          = no[3 * k + j];
                out[3 * N + 3 * n + j]  = nd[3 * k + j];
                out[6 * N + 3 * n + j]  = tr[3 * k + j];
            }
            for (int j = 0; j < 9; ++j)
                out[9 * N + 9 * n + j] = Rm[9 * k + j];
        }
    }
}

extern "C" void kernel_launch(void* const* d_in, const int* in_sizes, int n_in,
                              void* d_out, int out_size, void* d_ws, size_t ws_size,
                              hipStream_t stream) {
    const float* params = (const float*)d_in[0];
    const int*   idx    = (const int*)d_in[1];
    const float* o      = (const float*)d_in[2];
    const float* d      = (const float*)d_in[3];
    float*       out    = (float*)d_out;
    float*       cams   = (float*)d_ws;   // size*12 floats (48 KB for size=1000)

    int size = in_sizes[0] / 6;
    long long N = (long long)in_sizes[2] / 3;

    cam_precompute<<<(size + 255) / 256, 256, 0, stream>>>(params, cams, size);

    long long nq = (N + 3) / 4;
    int blocks = (int)((nq + 255) / 256);
    cam_apply<<<blocks, 256, 0, stream>>>(idx, (const f32x4*)o, (const f32x4*)d,
                                          (const f32x4*)cams, out, nq, N, size);
}

// Round 3
// 91.750 us; speedup vs baseline: 5.6806x; 5.6806x over previous
//
#include <hip/hip_runtime.h>
#include <math.h>

typedef float f32x4 __attribute__((ext_vector_type(4)));

// ---------------------------------------------------------------------------
// Kernel 1: per-camera precompute. cams[c*16] = {R[9], t[3], pad[4]}
// 64 B per camera -> every gather touches exactly one 64B-aligned region.
// ---------------------------------------------------------------------------
__global__ void cam_precompute(const float* __restrict__ params,
                               float* __restrict__ cams, int size) {
    int c = blockIdx.x * blockDim.x + threadIdx.x;
    if (c >= size) return;
    float a  = params[6 * c + 0];
    float b  = params[6 * c + 1];
    float cc = params[6 * c + 2];
    float t2 = a * a + b * b + cc * cc;
    float t  = sqrtf(t2);
    float sin_c, cos_c;
    if (t < 1e-8f) {
        sin_c = 1.0f;
        cos_c = 0.5f;
    } else {
        sin_c = sinf(t) / t;
        cos_c = (1.0f - cosf(t)) / t2;
    }
    float sa = sin_c * a, sb = sin_c * b, sc = sin_c * cc;
    float cab = cos_c * a * b, cac = cos_c * a * cc, cbc = cos_c * b * cc;

    float* o = cams + 16 * c;
    // R = I + sin_c*K + cos_c*K*K,  K = [[0,a,b],[-a,0,c],[-b,-c,0]]
    o[0] = 1.0f - cos_c * (a * a + b * b);
    o[1] =  sa - cbc;
    o[2] =  sb + cac;
    o[3] = -sa - cbc;
    o[4] = 1.0f - cos_c * (a * a + cc * cc);
    o[5] =  sc - cab;
    o[6] = -sb + cac;
    o[7] = -sc - cab;
    o[8] = 1.0f - cos_c * (b * b + cc * cc);
    o[9]  = params[6 * c + 3];
    o[10] = params[6 * c + 4];
    o[11] = params[6 * c + 5];
}

// ---------------------------------------------------------------------------
// Kernel 2: 1024-point tile per 256-thread block. LDS (36 KB) is used as a
// transpose arena so EVERY global load/store instruction is lane-contiguous
// (dense 64B lines). Compute-phase LDS access is word-stride 3 / 9, both
// coprime to 32 banks -> conflict-free.
// out layout (floats): [new_o: 3N][new_d: 3N][trans: 3N][R: 9N]
// ---------------------------------------------------------------------------
__launch_bounds__(256)
__global__ void cam_apply(const int* __restrict__ idx,
                          const float* __restrict__ of,
                          const float* __restrict__ df,
                          const f32x4* __restrict__ cams4,
                          float* __restrict__ out,
                          long long N) {
    __shared__ float lds[9216];   // 36 KB arena
    const int tid = threadIdx.x;
    const long long tileBase = (long long)blockIdx.x * 1024;

    if (tileBase + 1024 <= N) {
        // ---- Phase 1: stage o, d tiles (12 KB each), dense f32x4 loads ----
        const f32x4* o4 = (const f32x4*)(of + 3 * tileBase);   // 768 f32x4
        const f32x4* d4 = (const f32x4*)(df + 3 * tileBase);
        f32x4* A = (f32x4*)lds;              // o tile: floats [0, 3072)
        f32x4* B = (f32x4*)(lds + 3072);     // d tile: floats [3072, 6144)
#pragma unroll
        for (int j = 0; j < 3; ++j) A[tid + 256 * j] = o4[tid + 256 * j];
#pragma unroll
        for (int j = 0; j < 3; ++j) B[tid + 256 * j] = d4[tid + 256 * j];

        int id[4];
#pragma unroll
        for (int k = 0; k < 4; ++k) id[k] = idx[tileBase + tid + 256 * k];
        __syncthreads();

        // ---- Phase 2: compute 4 points/thread (n = tid + 256k) ----
        float cam[4][12], no[12], nd[12];
#pragma unroll
        for (int k = 0; k < 4; ++k) {
            int n = tid + 256 * k;
            float ox = lds[3 * n + 0], oy = lds[3 * n + 1], oz = lds[3 * n + 2];
            float dx = lds[3072 + 3 * n + 0], dy = lds[3072 + 3 * n + 1],
                  dz = lds[3072 + 3 * n + 2];
            const f32x4* cp = cams4 + 4 * (long long)id[k];
            f32x4 c0 = cp[0], c1 = cp[1], c2 = cp[2];
            cam[k][0] = c0[0]; cam[k][1] = c0[1]; cam[k][2]  = c0[2];
            cam[k][3] = c0[3]; cam[k][4] = c1[0]; cam[k][5]  = c1[1];
            cam[k][6] = c1[2]; cam[k][7] = c1[3]; cam[k][8]  = c2[0];
            cam[k][9] = c2[1]; cam[k][10] = c2[2]; cam[k][11] = c2[3];

            no[3 * k + 0] = c0[0] * ox + c0[1] * oy + c0[2] * oz + c2[1];
            no[3 * k + 1] = c0[3] * ox + c1[0] * oy + c1[1] * oz + c2[2];
            no[3 * k + 2] = c1[2] * ox + c1[3] * oy + c2[0] * oz + c2[3];

            nd[3 * k + 0] = c0[0] * dx + c0[1] * dy + c0[2] * dz;
            nd[3 * k + 1] = c0[3] * dx + c1[0] * dy + c1[1] * dz;
            nd[3 * k + 2] = c1[2] * dx + c1[3] * dy + c2[0] * dz;
        }
        __syncthreads();   // all o/d reads done; arena reusable

        // ---- Phase 3: write no/nd/tr to arena (stride-3, conflict-free) ----
#pragma unroll
        for (int k = 0; k < 4; ++k) {
            int n = tid + 256 * k;
            lds[3 * n + 0] = no[3 * k + 0];
            lds[3 * n + 1] = no[3 * k + 1];
            lds[3 * n + 2] = no[3 * k + 2];
            lds[3072 + 3 * n + 0] = nd[3 * k + 0];
            lds[3072 + 3 * n + 1] = nd[3 * k + 1];
            lds[3072 + 3 * n + 2] = nd[3 * k + 2];
            lds[6144 + 3 * n + 0] = cam[k][9];
            lds[6144 + 3 * n + 1] = cam[k][10];
            lds[6144 + 3 * n + 2] = cam[k][11];
        }
        __syncthreads();

        // ---- Phase 4: dense flush of new_o, new_d, trans ----
        const f32x4* src = (const f32x4*)lds;
        f32x4* g0 = (f32x4*)(out + 3 * tileBase);
        f32x4* g1 = (f32x4*)(out + 3 * N + 3 * tileBase);
        f32x4* g2 = (f32x4*)(out + 6 * N + 3 * tileBase);
#pragma unroll
        for (int j = 0; j < 3; ++j) g0[tid + 256 * j] = src[tid + 256 * j];
#pragma unroll
        for (int j = 0; j < 3; ++j) g1[tid + 256 * j] = src[768 + tid + 256 * j];
#pragma unroll
        for (int j = 0; j < 3; ++j) g2[tid + 256 * j] = src[1536 + tid + 256 * j];
        __syncthreads();   // flush reads done; arena reusable

        // ---- Phase 5: R tile (9216 floats = whole arena), stride-9 ----
#pragma unroll
        for (int k = 0; k < 4; ++k) {
            int n = tid + 256 * k;
#pragma unroll
            for (int j = 0; j < 9; ++j) lds[9 * n + j] = cam[k][j];
        }
        __syncthreads();

        f32x4* g3 = (f32x4*)(out + 9 * N + 9 * tileBase);
#pragma unroll
        for (int j = 0; j < 9; ++j) g3[tid + 256 * j] = src[tid + 256 * j];
    } else {
        // ---- tail tile: scalar guarded path ----
        for (int k = 0; k < 4; ++k) {
            long long n = tileBase + tid + 256 * k;
            if (n >= N) continue;
            int cid = idx[n];
            const f32x4* cp = cams4 + 4 * (long long)cid;
            f32x4 c0 = cp[0], c1 = cp[1], c2 = cp[2];
            float ox = of[3 * n + 0], oy = of[3 * n + 1], oz = of[3 * n + 2];
            float dx = df[3 * n + 0], dy = df[3 * n + 1], dz = df[3 * n + 2];

            out[3 * n + 0] = c0[0] * ox + c0[1] * oy + c0[2] * oz + c2[1];
            out[3 * n + 1] = c0[3] * ox + c1[0] * oy + c1[1] * oz + c2[2];
            out[3 * n + 2] = c1[2] * ox + c1[3] * oy + c2[0] * oz + c2[3];

            out[3 * N + 3 * n + 0] = c0[0] * dx + c0[1] * dy + c0[2] * dz;
            out[3 * N + 3 * n + 1] = c0[3] * dx + c1[0] * dy + c1[1] * dz;
            out[3 * N + 3 * n + 2] = c1[2] * dx + c1[3] * dy + c2[0] * dz;

            out[6 * N + 3 * n + 0] = c2[1];
            out[6 * N + 3 * n + 1] = c2[2];
            out[6 * N + 3 * n + 2] = c2[3];

            float Rv[9] = {c0[0], c0[1], c0[2], c0[3], c1[0], c1[1],
                           c1[2], c1[3], c2[0]};
            for (int j = 0; j < 9; ++j) out[9 * N + 9 * n + j] = Rv[j];
        }
    }
}

extern "C" void kernel_launch(void* const* d_in, const int* in_sizes, int n_in,
                              void* d_out, int out_size, void* d_ws, size_t ws_size,
                              hipStream_t stream) {
    const float* params = (const float*)d_in[0];
    const int*   idx    = (const int*)d_in[1];
    const float* o      = (const float*)d_in[2];
    const float* d      = (const float*)d_in[3];
    float*       out    = (float*)d_out;
    float*       cams   = (float*)d_ws;   // size*16 floats (64 KB for size=1000)

    int size = in_sizes[0] / 6;
    long long N = (long long)in_sizes[2] / 3;

    cam_precompute<<<(size + 255) / 256, 256, 0, stream>>>(params, cams, size);

    int blocks = (int)((N + 1023) / 1024);
    cam_apply<<<blocks, 256, 0, stream>>>(idx, o, d, (const f32x4*)cams,
                                          out, N);
}